// Round 13
// baseline (705.120 us; speedup 1.0000x reference)
//
#include <hip/hip_runtime.h>
#include <hip/hip_bf16.h>

typedef __attribute__((ext_vector_type(8))) short short8;
typedef __attribute__((ext_vector_type(16))) float floatx16;
typedef __attribute__((ext_vector_type(4))) float floatx4;

#define AS1 __attribute__((address_space(1)))
#define AS3 __attribute__((address_space(3)))

constexpr int MM = 65536;   // batch
constexpr int KK = 512;     // inner dim
constexpr int NN = 512;     // out dim per layer

#define GK 32

// round-to-nearest-even fp32 -> bf16 (bit-level, finite inputs)
__device__ __forceinline__ unsigned short bf16_rn(float v) {
  unsigned u = __float_as_uint(v);
  return (unsigned short)((u + 0x7FFFu + ((u >> 16) & 1u)) >> 16);
}
__device__ __forceinline__ float bf16_to_f32(unsigned short h) {
  return __uint_as_float((unsigned)h << 16);
}

// ---------------------------------------------------------------------------
// ALL weight prep in ONE launch: blocks 0..767 -> W0/W1/W2 hi/lo splits;
// 768..775 -> Wc split; 776..903 -> Wg mu-rows pack + wgb.
// ---------------------------------------------------------------------------
__global__ __launch_bounds__(256) void prep_all(
    const float* __restrict__ W0, const float* __restrict__ W1,
    const float* __restrict__ W2, const float* __restrict__ Wc,
    const float* __restrict__ Wg, const float* __restrict__ bg,
    unsigned short* __restrict__ w0h, unsigned short* __restrict__ w0l,
    unsigned short* __restrict__ w1h, unsigned short* __restrict__ w1l,
    unsigned short* __restrict__ w2h, unsigned short* __restrict__ w2l,
    unsigned short* __restrict__ wch, unsigned short* __restrict__ wcl,
    unsigned short* __restrict__ wgh, float* __restrict__ wgb) {
  const int b = blockIdx.x;
  if (b < 776) {
    const float* src; unsigned short* h; unsigned short* l; int i;
    if (b < 256)      { src = W0; h = w0h; l = w0l; i = b * 256 + threadIdx.x; }
    else if (b < 512) { src = W1; h = w1h; l = w1l; i = (b - 256) * 256 + threadIdx.x; }
    else if (b < 768) { src = W2; h = w2h; l = w2l; i = (b - 512) * 256 + threadIdx.x; }
    else              { src = Wc; h = wch; l = wcl; i = (b - 768) * 256 + threadIdx.x; }
    float4 v = ((const float4*)src)[i];
    ushort4 hv, lv;
    hv.x = bf16_rn(v.x); lv.x = bf16_rn(v.x - bf16_to_f32(hv.x));
    hv.y = bf16_rn(v.y); lv.y = bf16_rn(v.y - bf16_to_f32(hv.y));
    hv.z = bf16_rn(v.z); lv.z = bf16_rn(v.z - bf16_to_f32(hv.z));
    hv.w = bf16_rn(v.w); lv.w = bf16_rn(v.w - bf16_to_f32(hv.w));
    ((ushort4*)h)[i] = hv;
    ((ushort4*)l)[i] = lv;
  } else {
    int gid = (b - 776) * 256 + threadIdx.x;   // 0..32767
    int r = gid >> 7;
    int c4 = (gid & 127) * 4;
    int k = r >> 4, e = r & 15;
    float4 v = *(const float4*)(Wg + ((size_t)k * 32 + e) * 512 + c4);
    ushort4 h;
    h.x = bf16_rn(v.x); h.y = bf16_rn(v.y); h.z = bf16_rn(v.z); h.w = bf16_rn(v.w);
    *(ushort4*)(wgh + (size_t)r * 512 + c4) = h;
    if (c4 == 0) wgb[r] = bg[k * 32 + e];
  }
}

// ---------------------------------------------------------------------------
// GEMM layers 2,3: 4-phase interleave; R15: ALL 8 prefetch loads issued at
// p0 (was 2/phase) -> every tile-t load gets a FULL tile (~1000 cyc) of
// latency cover before vmcnt(8) demands it (was 1-4 phases). Barriers/K-tile
// stay at 5 (R14 thinning).
// ---------------------------------------------------------------------------
template<bool RELU>
__global__ __launch_bounds__(512, 1) void gemm_mfma(
    const unsigned short* __restrict__ Ah, const unsigned short* __restrict__ Al,
    const unsigned short* __restrict__ Wh, const unsigned short* __restrict__ Wl,
    const float* __restrict__ bias,
    unsigned short* __restrict__ Ch, unsigned short* __restrict__ Cl) {
  __shared__ __align__(16) unsigned short smem[65536];   // 128 KB
  const int tid = threadIdx.x;
  const int lane = tid & 63;
  const int wid = tid >> 6;
  const int wr = wid >> 2;
  const int wc = wid & 3;
  const int nwg = gridDim.x;
  const int hw  = blockIdx.x;
  const int logical = (hw & 7) * (nwg >> 3) + (hw >> 3);
  const int bm = logical >> 1, bn = logical & 1;
  const size_t Abase = (size_t)bm * 256 * KK;
  const size_t Bbase = (size_t)bn * 256 * KK;

  const int sarr  = wid >> 1;
  const int rbase = (wid & 1) * 128;
  const unsigned short* gsrc = (sarr == 0) ? Ah : (sarr == 1) ? Al
                             : (sarr == 2) ? Wh : Wl;
  const size_t tb = (sarr < 2) ? Abase : Bbase;
  const int rowl = lane >> 2;
  const int gch  = (lane & 3) ^ ((lane >> 3) & 3);
  const unsigned short* gbase = gsrc + tb + (size_t)(rbase + rowl) * KK + gch * 8;
  unsigned short* ldst = smem + sarr * 8192 + rbase * 32;

  auto stage8 = [&](int buf, int kk) {
#pragma unroll
    for (int j = 0; j < 8; ++j) {
      __builtin_amdgcn_global_load_lds(
          (const AS1 unsigned int*)(gbase + (size_t)(j * 16) * KK + kk),
          (AS3 unsigned int*)(ldst + buf * 32768 + j * 16 * 32),
          16, 0, 0);
    }
  };

  floatx16 acc[4][2];
#pragma unroll
  for (int i = 0; i < 4; ++i)
#pragma unroll
    for (int j = 0; j < 2; ++j)
#pragma unroll
      for (int r = 0; r < 16; ++r) acc[i][j][r] = 0.f;

  stage8(0, 0);

  const int swz = (lane >> 1) & 3;
#pragma unroll
  for (int t = 0; t < 16; ++t) {
    const int cur = t & 1;
    const unsigned short* base = smem + cur * 32768;
    short8 fbh[2], fbl[2];
#pragma unroll
    for (int p = 0; p < 4; ++p) {
      const int ks = p >> 1, h = p & 1;
      const int ch = ks * 2 + (lane >> 5);
      const int sw = (ch ^ swz) * 8;
      short8 fah[2], fal[2];

      if (p == 0) {
        if (t < 15) {
          stage8(cur ^ 1, (t + 1) * GK);               // all 8, max slack
          asm volatile("s_waitcnt vmcnt(8)" ::: "memory");  // retire tile t
        } else {
          asm volatile("s_waitcnt vmcnt(0)" ::: "memory");
        }
        __builtin_amdgcn_s_barrier();                  // tile t visible
        __builtin_amdgcn_sched_barrier(0);
      }

#pragma unroll
      for (int q = 0; q < 2; ++q) {
        int row = wr * 128 + (h * 2 + q) * 32 + (lane & 31);
        fah[q] = *(const short8*)(base + row * 32 + sw);
        fal[q] = *(const short8*)(base + 8192 + row * 32 + sw);
      }
      if (h == 0) {
#pragma unroll
        for (int si = 0; si < 2; ++si) {
          int col = wc * 64 + si * 32 + (lane & 31);
          fbh[si] = *(const short8*)(base + 16384 + col * 32 + sw);
          fbl[si] = *(const short8*)(base + 24576 + col * 32 + sw);
        }
      }

      __builtin_amdgcn_s_setprio(1);
#pragma unroll
      for (int q = 0; q < 2; ++q)
#pragma unroll
        for (int si = 0; si < 2; ++si) {
          const int ri = h * 2 + q;
          acc[ri][si] = __builtin_amdgcn_mfma_f32_32x32x16_bf16(fah[q], fbh[si], acc[ri][si], 0, 0, 0);
          acc[ri][si] = __builtin_amdgcn_mfma_f32_32x32x16_bf16(fah[q], fbl[si], acc[ri][si], 0, 0, 0);
          acc[ri][si] = __builtin_amdgcn_mfma_f32_32x32x16_bf16(fal[q], fbh[si], acc[ri][si], 0, 0, 0);
        }
      __builtin_amdgcn_s_setprio(0);
      __builtin_amdgcn_sched_barrier(0);
      __builtin_amdgcn_s_barrier();                    // end-phase
    }
  }

  float bv[2];
#pragma unroll
  for (int si = 0; si < 2; ++si)
    bv[si] = bias[bn * 256 + wc * 64 + si * 32 + (lane & 31)];

  unsigned* lds32 = (unsigned*)smem;
#pragma unroll
  for (int ri = 0; ri < 4; ++ri) {
    __syncthreads();
#pragma unroll
    for (int si = 0; si < 2; ++si) {
      int lcol = wc * 64 + si * 32 + (lane & 31);
#pragma unroll
      for (int r = 0; r < 16; ++r) {
        int frow = (r & 3) + 8 * (r >> 2) + 4 * (lane >> 5);
        float v = acc[ri][si][r] + bv[si];
        if (RELU) v = fmaxf(v, 0.f);
        unsigned short h = bf16_rn(v);
        unsigned short lo = bf16_rn(v - bf16_to_f32(h));
        lds32[(wr * 32 + frow) * 256 + lcol] = (unsigned)h | ((unsigned)lo << 16);
      }
    }
    __syncthreads();
#pragma unroll
    for (int p = 0; p < 8; ++p) {
      int c = tid + p * 512;
      int lrow = c >> 6;
      int cc = (c & 63) * 4;
      uint4 d = *(const uint4*)&lds32[lrow * 256 + cc];
      ushort4 hv, lv;
      hv.x = (unsigned short)(d.x); lv.x = (unsigned short)(d.x >> 16);
      hv.y = (unsigned short)(d.y); lv.y = (unsigned short)(d.y >> 16);
      hv.z = (unsigned short)(d.z); lv.z = (unsigned short)(d.z >> 16);
      hv.w = (unsigned short)(d.w); lv.w = (unsigned short)(d.w >> 16);
      int grow = bm * 256 + (lrow >> 5) * 128 + ri * 32 + (lrow & 31);
      size_t gi = (size_t)grow * NN + bn * 256 + cc;
      *(ushort4*)&Ch[gi] = hv;
      *(ushort4*)&Cl[gi] = lv;
    }
  }
}

// ---------------------------------------------------------------------------
// GEMM layer 1: A = x (fp32) split on the fly. R10 version verbatim
// (measured 154 us at healthy clocks) -- do not touch (R11 lesson).
// ---------------------------------------------------------------------------
__global__ __launch_bounds__(512, 1) void gemm_x(
    const float* __restrict__ X,
    const unsigned short* __restrict__ Wh, const unsigned short* __restrict__ Wl,
    const float* __restrict__ bias,
    unsigned short* __restrict__ Ch, unsigned short* __restrict__ Cl) {
  __shared__ __align__(16) unsigned short smem[65536];   // 128 KB
  const int tid = threadIdx.x;
  const int lane = tid & 63;
  const int wid = tid >> 6;
  const int wr = wid >> 2;
  const int wc = wid & 3;
  const int nwg = gridDim.x;
  const int hw  = blockIdx.x;
  const int logical = (hw & 7) * (nwg >> 3) + (hw >> 3);
  const int bm = logical >> 1, bn = logical & 1;

  const int barr = wid >> 2;
  const int brb  = (wid & 3) * 64;
  const int rowl = lane >> 2;
  const int gch  = (lane & 3) ^ ((lane >> 3) & 3);
  const unsigned short* gbB = (barr ? Wl : Wh) + (size_t)bn * 256 * KK
                            + (size_t)(brb + rowl) * KK + gch * 8;
  unsigned short* ldB = smem + (2 + barr) * 8192 + brb * 32;

  auto stageB = [&](int buf, int kk) {
#pragma unroll
    for (int j = 0; j < 4; ++j) {
      __builtin_amdgcn_global_load_lds(
          (const AS1 unsigned int*)(gbB + (size_t)(j * 16) * KK + kk),
          (AS3 unsigned int*)(ldB + buf * 32768 + j * 16 * 32),
          16, 0, 0);
    }
  };

  const int arow = lane >> 3;
  const int akc  = lane & 7;
  const float* gx = X + ((size_t)(bm * 256 + wid * 32) + arow) * KK + akc * 4;
  auto loadA = [&](int kk, float4* av) {
#pragma unroll
    for (int j = 0; j < 4; ++j)
      av[j] = *(const float4*)(gx + (size_t)(j * 8) * KK + kk);
  };
  const int apc = ((akc >> 1) ^ ((arow >> 1) & 3));
  const int aoff = (wid * 32 + arow) * 32 + apc * 8 + (akc & 1) * 4;
  auto writeA = [&](int buf, const float4* av) {
#pragma unroll
    for (int j = 0; j < 4; ++j) {
      ushort4 hv, lv;
      hv.x = bf16_rn(av[j].x); lv.x = bf16_rn(av[j].x - bf16_to_f32(hv.x));
      hv.y = bf16_rn(av[j].y); lv.y = bf16_rn(av[j].y - bf16_to_f32(hv.y));
      hv.z = bf16_rn(av[j].z); lv.z = bf16_rn(av[j].z - bf16_to_f32(hv.z));
      hv.w = bf16_rn(av[j].w); lv.w = bf16_rn(av[j].w - bf16_to_f32(hv.w));
      int o = buf * 32768 + aoff + j * 8 * 32;
      *(ushort4*)(smem + o) = hv;
      *(ushort4*)(smem + 8192 + o) = lv;
    }
  };

  floatx16 acc[4][2];
#pragma unroll
  for (int i = 0; i < 4; ++i)
#pragma unroll
    for (int j = 0; j < 2; ++j)
#pragma unroll
      for (int r = 0; r < 16; ++r) acc[i][j][r] = 0.f;

  {
    float4 av0[4];
    stageB(0, 0);
    loadA(0, av0);
    asm volatile("s_waitcnt vmcnt(0)" ::: "memory");
    writeA(0, av0);
    asm volatile("s_waitcnt lgkmcnt(0)" ::: "memory");
    __builtin_amdgcn_s_barrier();
  }

  const int swz = (lane >> 1) & 3;
#pragma unroll
  for (int t = 0; t < 16; ++t) {
    const int cur = t & 1;
    const unsigned short* base = smem + cur * 32768;
    short8 fbh[2], fbl[2];
    float4 av[4];
#pragma unroll
    for (int p = 0; p < 4; ++p) {
      const int ks = p >> 1, h = p & 1;
      const int ch = ks * 2 + (lane >> 5);
      const int sw = (ch ^ swz) * 8;
      short8 fah[2], fal[2];

      if (p == 0 && t < 15) {
        stageB(cur ^ 1, (t + 1) * GK);
        loadA((t + 1) * GK, av);
      }

#pragma unroll
      for (int q = 0; q < 2; ++q) {
        int row = wr * 128 + (h * 2 + q) * 32 + (lane & 31);
        fah[q] = *(const short8*)(base + row * 32 + sw);
        fal[q] = *(const short8*)(base + 8192 + row * 32 + sw);
      }
      if (h == 0) {
#pragma unroll
        for (int si = 0; si < 2; ++si) {
          int col = wc * 64 + si * 32 + (lane & 31);
          fbh[si] = *(const short8*)(base + 16384 + col * 32 + sw);
          fbl[si] = *(const short8*)(base + 24576 + col * 32 + sw);
        }
      }

      __builtin_amdgcn_s_setprio(1);
#pragma unroll
      for (int q = 0; q < 2; ++q)
#pragma unroll
        for (int si = 0; si < 2; ++si) {
          const int ri = h * 2 + q;
          acc[ri][si] = __builtin_amdgcn_mfma_f32_32x32x16_bf16(fah[q], fbh[si], acc[ri][si], 0, 0, 0);
          acc[ri][si] = __builtin_amdgcn_mfma_f32_32x32x16_bf16(fah[q], fbl[si], acc[ri][si], 0, 0, 0);
          acc[ri][si] = __builtin_amdgcn_mfma_f32_32x32x16_bf16(fal[q], fbh[si], acc[ri][si], 0, 0, 0);
        }
      __builtin_amdgcn_s_setprio(0);
      __builtin_amdgcn_sched_barrier(0);

      if (p == 3) {
        if (t < 15) {
          asm volatile("s_waitcnt vmcnt(0)" ::: "memory");
          writeA(cur ^ 1, av);
        }
        asm volatile("s_waitcnt lgkmcnt(0)" ::: "memory");
        __builtin_amdgcn_s_barrier();
      } else {
        __builtin_amdgcn_s_barrier();
      }
      __builtin_amdgcn_sched_barrier(0);
    }
  }

  float bv[2];
#pragma unroll
  for (int si = 0; si < 2; ++si)
    bv[si] = bias[bn * 256 + wc * 64 + si * 32 + (lane & 31)];

  unsigned* lds32 = (unsigned*)smem;
#pragma unroll
  for (int ri = 0; ri < 4; ++ri) {
    __syncthreads();
#pragma unroll
    for (int si = 0; si < 2; ++si) {
      int lcol = wc * 64 + si * 32 + (lane & 31);
#pragma unroll
      for (int r = 0; r < 16; ++r) {
        int frow = (r & 3) + 8 * (r >> 2) + 4 * (lane >> 5);
        float v = fmaxf(acc[ri][si][r] + bv[si], 0.f);
        unsigned short h = bf16_rn(v);
        unsigned short lo = bf16_rn(v - bf16_to_f32(h));
        lds32[(wr * 32 + frow) * 256 + lcol] = (unsigned)h | ((unsigned)lo << 16);
      }
    }
    __syncthreads();
#pragma unroll
    for (int p = 0; p < 8; ++p) {
      int c = tid + p * 512;
      int lrow = c >> 6;
      int cc = (c & 63) * 4;
      uint4 d = *(const uint4*)&lds32[lrow * 256 + cc];
      ushort4 hv, lv;
      hv.x = (unsigned short)(d.x); lv.x = (unsigned short)(d.x >> 16);
      hv.y = (unsigned short)(d.y); lv.y = (unsigned short)(d.y >> 16);
      hv.z = (unsigned short)(d.z); lv.z = (unsigned short)(d.z >> 16);
      hv.w = (unsigned short)(d.w); lv.w = (unsigned short)(d.w >> 16);
      int grow = bm * 256 + (lrow >> 5) * 128 + ri * 32 + (lrow & 31);
      size_t gi = (size_t)grow * NN + bn * 256 + cc;
      *(ushort4*)&Ch[gi] = hv;
      *(ushort4*)&Cl[gi] = lv;
    }
  }
}

// ---------------------------------------------------------------------------
// FUSED HEAD: R15: all 6 prefetch loads issued at p0 (was 2/2/2), vmcnt(6)
// -> tile-t loads get a full tile of latency cover (1 block/CU, thin TLP).
// ---------------------------------------------------------------------------
__global__ __launch_bounds__(512, 1) void gemm_head(
    const unsigned short* __restrict__ mh, const unsigned short* __restrict__ ml,
    const unsigned short* __restrict__ wgh, const float* __restrict__ wgb,
    const unsigned short* __restrict__ wch, const unsigned short* __restrict__ wcl,
    const float* __restrict__ bc,
    float* __restrict__ y_out, float* __restrict__ z_out) {
  __shared__ __align__(16) unsigned short smem[65792];
  const int tid = threadIdx.x;
  const int lane = tid & 63;
  const int wid = tid >> 6;
  const int wr = wid >> 2;
  const int wcs = wid & 3;
  const int bm = blockIdx.x;
  const int fr = lane & 15, fq = lane >> 4;

  const unsigned short* baseA0 = mh + (size_t)bm * 256 * KK;
  const unsigned short* baseA1 = ml + (size_t)bm * 256 * KK;
  const int rowl = lane >> 2;
  const int gch  = (lane & 3) ^ ((lane >> 3) & 3);
  const unsigned short* gb[6];
  int ldo[6];
#pragma unroll
  for (int i = 0; i < 6; ++i) {
    int s = wid * 6 + i;
    int arr = s >> 4, seg = s & 15;
    const unsigned short* b = (arr == 0) ? baseA0 : (arr == 1) ? baseA1 : wgh;
    gb[i] = b + (size_t)(seg * 16 + rowl) * KK + gch * 8;
    ldo[i] = arr * 8192 + seg * 16 * 32;
  }
  auto stage6 = [&](int buf, int kk) {
#pragma unroll
    for (int i = 0; i < 6; ++i) {
      __builtin_amdgcn_global_load_lds(
          (const AS1 unsigned int*)(gb[i] + kk),
          (AS3 unsigned int*)(smem + buf * 24576 + ldo[i]),
          16, 0, 0);
    }
  };

  const float bcv = bc[fr];
  int colv[2]; float bvmu[2];
#pragma unroll
  for (int si = 0; si < 2; ++si) {
    colv[si] = wcs * 64 + si * 32 + (lane & 31);
    bvmu[si] = wgb[colv[si]];
  }

  {
    short8 r0[2], r1[2];
#pragma unroll
    for (int q = 0; q < 2; ++q) {
      int c = tid + q * 512;
      int row = c >> 6, cc = (c & 63) * 8;
      r0[q] = *(const short8*)(wch + row * 512 + cc);
      r1[q] = *(const short8*)(wcl + row * 512 + cc);
    }
#pragma unroll
    for (int q = 0; q < 2; ++q) {
      int c = tid + q * 512;
      int row = c >> 6, cc = (c & 63) * 8;
      *(short8*)(smem + 49152 + row * 520 + cc) = r0[q];
      *(short8*)(smem + 57472 + row * 520 + cc) = r1[q];
    }
    stage6(0, 0);
    asm volatile("s_waitcnt vmcnt(0) lgkmcnt(0)" ::: "memory");
    __builtin_amdgcn_s_barrier();
  }

  floatx16 accm[4][2];
#pragma unroll
  for (int i = 0; i < 4; ++i)
#pragma unroll
    for (int j = 0; j < 2; ++j)
#pragma unroll
      for (int r = 0; r < 16; ++r) accm[i][j][r] = 0.f;
  floatx4 accl0 = {0.f, 0.f, 0.f, 0.f};
  floatx4 accl1 = {0.f, 0.f, 0.f, 0.f};

  const int swz = (lane >> 1) & 3;
  const int lsw = (fq ^ ((fr >> 1) & 3)) * 8;
#pragma unroll
  for (int t = 0; t < 16; ++t) {
    const int cur = t & 1;
    const unsigned short* base = smem + cur * 24576;
    short8 fb[2];
#pragma unroll
    for (int p = 0; p < 4; ++p) {
      const int ks = p >> 1, h = p & 1;
      const int ch = ks * 2 + (lane >> 5);
      const int sw = (ch ^ swz) * 8;
      short8 fa[2];

      if (p == 0) {
        if (t < 15) {
          stage6(cur ^ 1, (t + 1) * GK);               // all 6, max slack
          asm volatile("s_waitcnt vmcnt(6)" ::: "memory");  // retire tile t
        } else {
          asm volatile("s_waitcnt vmcnt(0)" ::: "memory");
        }
        __builtin_amdgcn_s_barrier();
        __builtin_amdgcn_sched_barrier(0);
      }

#pragma unroll
      for (int q = 0; q < 2; ++q) {
        int row = wr * 128 + (h * 2 + q) * 32 + (lane & 31);
        fa[q] = *(const short8*)(base + row * 32 + sw);
      }
      if (h == 0) {
#pragma unroll
        for (int si = 0; si < 2; ++si) {
          int col = wcs * 64 + si * 32 + (lane & 31);
          fb[si] = *(const short8*)(base + 16384 + col * 32 + sw);
        }
      }
      short8 lah, lal, lbh, lbl;
      if (p & 1) {
        const int g = p >> 1;
        int lrow = wid * 32 + g * 16 + fr;
        lah = *(const short8*)(base + lrow * 32 + lsw);
        lal = *(const short8*)(base + 8192 + lrow * 32 + lsw);
        lbh = *(const short8*)(smem + 49152 + fr * 520 + t * 32 + fq * 8);
        lbl = *(const short8*)(smem + 57472 + fr * 520 + t * 32 + fq * 8);
      }

      __builtin_amdgcn_s_setprio(1);
#pragma unroll
      for (int q = 0; q < 2; ++q)
#pragma unroll
        for (int si = 0; si < 2; ++si)
          accm[h * 2 + q][si] = __builtin_amdgcn_mfma_f32_32x32x16_bf16(fa[q], fb[si], accm[h * 2 + q][si], 0, 0, 0);
      if (p == 1) {
        accl0 = __builtin_amdgcn_mfma_f32_16x16x32_bf16(lah, lbh, accl0, 0, 0, 0);
        accl0 = __builtin_amdgcn_mfma_f32_16x16x32_bf16(lah, lbl, accl0, 0, 0, 0);
        accl0 = __builtin_amdgcn_mfma_f32_16x16x32_bf16(lal, lbh, accl0, 0, 0, 0);
      }
      if (p == 3) {
        accl1 = __builtin_amdgcn_mfma_f32_16x16x32_bf16(lah, lbh, accl1, 0, 0, 0);
        accl1 = __builtin_amdgcn_mfma_f32_16x16x32_bf16(lah, lbl, accl1, 0, 0, 0);
        accl1 = __builtin_amdgcn_mfma_f32_16x16x32_bf16(lal, lbh, accl1, 0, 0, 0);
      }
      __builtin_amdgcn_s_setprio(0);
      __builtin_amdgcn_sched_barrier(0);
      __builtin_amdgcn_s_barrier();                    // end-phase
    }
  }

  __syncthreads();
  float* slog = (float*)smem;                 // [256][17]
  float* yl = slog + 256 * 17;                // [256]
#pragma unroll
  for (int r = 0; r < 4; ++r) {
    slog[(wid * 32 + 0 * 16 + fq * 4 + r) * 17 + fr] = accl0[r] + bcv;
    slog[(wid * 32 + 1 * 16 + fq * 4 + r) * 17 + fr] = accl1[r] + bcv;
  }
  __syncthreads();
  if (tid < 256) {
    float best = slog[tid * 17];
    int bi = 0;
#pragma unroll
    for (int j = 1; j < 16; ++j) {            // strict >: first-max = np argmax
      float v = slog[tid * 17 + j];
      if (v > best) { best = v; bi = j; }
    }
    yl[tid] = (float)bi;
    y_out[(size_t)bm * 256 + tid] = (float)bi;
  }
  __syncthreads();
#pragma unroll
  for (int ri = 0; ri < 4; ++ri)
#pragma unroll
    for (int r = 0; r < 16; ++r) {
      int rowL = wr * 128 + ri * 32 + (r & 3) + 8 * (r >> 2) + 4 * (lane >> 5);
      int yv = (int)yl[rowL];
#pragma unroll
      for (int si = 0; si < 2; ++si) {
        if ((colv[si] >> 4) == yv)
          z_out[((size_t)bm * 256 + rowL) * 16 + (colv[si] & 15)] = accm[ri][si][r] + bvmu[si];
      }
    }
}

extern "C" void kernel_launch(void* const* d_in, const int* in_sizes, int n_in,
                              void* d_out, int out_size, void* d_ws, size_t ws_size,
                              hipStream_t stream) {
  const float* x  = (const float*)d_in[0];
  const float* W0 = (const float*)d_in[1];
  const float* b0 = (const float*)d_in[2];
  const float* W1 = (const float*)d_in[3];
  const float* b1 = (const float*)d_in[4];
  const float* W2 = (const float*)d_in[5];
  const float* b2 = (const float*)d_in[6];
  const float* Wc = (const float*)d_in[7];
  const float* bc = (const float*)d_in[8];
  const float* Wg = (const float*)d_in[9];
  const float* bg = (const float*)d_in[10];

  const size_t NEL = (size_t)MM * KK;
  unsigned short* Ah = (unsigned short*)d_ws;           // 64 MiB each
  unsigned short* Al = Ah + NEL;
  unsigned short* Bh = Al + NEL;
  unsigned short* Bl = Bh + NEL;
  // small weight buffers past the 4 big ones (prep_all runs first)
  unsigned short* wtail = Bl + NEL;
  unsigned short* wch = wtail;
  unsigned short* wcl = wtail + 8192;
  unsigned short* wgh = wtail + 16384;
  float* wgb = (float*)(wtail + 16384 + 131072);

  unsigned short* w0h = (unsigned short*)d_out;
  unsigned short* w0l = w0h + 262144;
  unsigned short* w1h = w0l + 262144;
  unsigned short* w1l = w1h + 262144;
  unsigned short* w2h = w1l + 262144;
  unsigned short* w2l = w2h + 262144;

  float* z_out = (float*)d_out;
  float* y_out = z_out + (size_t)MM * 16;               // at +4 MiB, clear of w-splits

  prep_all<<<904, 256, 0, stream>>>(W0, W1, W2, Wc, Wg, bg,
                                    w0h, w0l, w1h, w1l, w2h, w2l,
                                    wch, wcl, wgh, wgb);

  const int ngrid = (MM / 256) * (NN / 256);            // 512, %8==0
  gemm_x<<<ngrid, 512, 0, stream>>>(x, w0h, w0l, b0, Bh, Bl);
  gemm_mfma<true ><<<ngrid, 512, 0, stream>>>(Bh, Bl, w1h, w1l, b1, Ah, Al);
  gemm_mfma<false><<<ngrid, 512, 0, stream>>>(Ah, Al, w2h, w2l, b2, Bh, Bl);

  gemm_head<<<MM / 256, 512, 0, stream>>>(Bh, Bl, wgh, wgb, wch, wcl, bc, y_out, z_out);
}

// Round 14
// 563.548 us; speedup vs baseline: 1.2512x; 1.2512x over previous
//
#include <hip/hip_runtime.h>
#include <hip/hip_bf16.h>

typedef __attribute__((ext_vector_type(8))) short short8;
typedef __attribute__((ext_vector_type(16))) float floatx16;
typedef __attribute__((ext_vector_type(4))) float floatx4;

#define AS1 __attribute__((address_space(1)))
#define AS3 __attribute__((address_space(3)))

constexpr int MM = 65536;   // batch
constexpr int KK = 512;     // inner dim
constexpr int NN = 512;     // out dim per layer

#define GK 32

// round-to-nearest-even fp32 -> bf16 (bit-level, finite inputs)
__device__ __forceinline__ unsigned short bf16_rn(float v) {
  unsigned u = __float_as_uint(v);
  return (unsigned short)((u + 0x7FFFu + ((u >> 16) & 1u)) >> 16);
}
__device__ __forceinline__ float bf16_to_f32(unsigned short h) {
  return __uint_as_float((unsigned)h << 16);
}

// ---------------------------------------------------------------------------
// ALL weight prep in ONE launch: blocks 0..767 -> W0/W1/W2 hi/lo splits;
// 768..775 -> Wc split; 776..903 -> Wg mu-rows pack + wgb.
// ---------------------------------------------------------------------------
__global__ __launch_bounds__(256) void prep_all(
    const float* __restrict__ W0, const float* __restrict__ W1,
    const float* __restrict__ W2, const float* __restrict__ Wc,
    const float* __restrict__ Wg, const float* __restrict__ bg,
    unsigned short* __restrict__ w0h, unsigned short* __restrict__ w0l,
    unsigned short* __restrict__ w1h, unsigned short* __restrict__ w1l,
    unsigned short* __restrict__ w2h, unsigned short* __restrict__ w2l,
    unsigned short* __restrict__ wch, unsigned short* __restrict__ wcl,
    unsigned short* __restrict__ wgh, float* __restrict__ wgb) {
  const int b = blockIdx.x;
  if (b < 776) {
    const float* src; unsigned short* h; unsigned short* l; int i;
    if (b < 256)      { src = W0; h = w0h; l = w0l; i = b * 256 + threadIdx.x; }
    else if (b < 512) { src = W1; h = w1h; l = w1l; i = (b - 256) * 256 + threadIdx.x; }
    else if (b < 768) { src = W2; h = w2h; l = w2l; i = (b - 512) * 256 + threadIdx.x; }
    else              { src = Wc; h = wch; l = wcl; i = (b - 768) * 256 + threadIdx.x; }
    float4 v = ((const float4*)src)[i];
    ushort4 hv, lv;
    hv.x = bf16_rn(v.x); lv.x = bf16_rn(v.x - bf16_to_f32(hv.x));
    hv.y = bf16_rn(v.y); lv.y = bf16_rn(v.y - bf16_to_f32(hv.y));
    hv.z = bf16_rn(v.z); lv.z = bf16_rn(v.z - bf16_to_f32(hv.z));
    hv.w = bf16_rn(v.w); lv.w = bf16_rn(v.w - bf16_to_f32(hv.w));
    ((ushort4*)h)[i] = hv;
    ((ushort4*)l)[i] = lv;
  } else {
    int gid = (b - 776) * 256 + threadIdx.x;   // 0..32767
    int r = gid >> 7;
    int c4 = (gid & 127) * 4;
    int k = r >> 4, e = r & 15;
    float4 v = *(const float4*)(Wg + ((size_t)k * 32 + e) * 512 + c4);
    ushort4 h;
    h.x = bf16_rn(v.x); h.y = bf16_rn(v.y); h.z = bf16_rn(v.z); h.w = bf16_rn(v.w);
    *(ushort4*)(wgh + (size_t)r * 512 + c4) = h;
    if (c4 == 0) wgb[r] = bg[k * 32 + e];
  }
}

// ---------------------------------------------------------------------------
// GEMM layers 2,3: 4-phase interleave; all 8 prefetch loads issued at p0 ->
// every tile-t load gets a full tile (~1000 cyc) of latency cover before
// vmcnt(8) demands it. Barriers/K-tile: 5.
// ---------------------------------------------------------------------------
template<bool RELU>
__global__ __launch_bounds__(512, 1) void gemm_mfma(
    const unsigned short* __restrict__ Ah, const unsigned short* __restrict__ Al,
    const unsigned short* __restrict__ Wh, const unsigned short* __restrict__ Wl,
    const float* __restrict__ bias,
    unsigned short* __restrict__ Ch, unsigned short* __restrict__ Cl) {
  __shared__ __align__(16) unsigned short smem[65536];   // 128 KB
  const int tid = threadIdx.x;
  const int lane = tid & 63;
  const int wid = tid >> 6;
  const int wr = wid >> 2;
  const int wc = wid & 3;
  const int nwg = gridDim.x;
  const int hw  = blockIdx.x;
  const int logical = (hw & 7) * (nwg >> 3) + (hw >> 3);
  const int bm = logical >> 1, bn = logical & 1;
  const size_t Abase = (size_t)bm * 256 * KK;
  const size_t Bbase = (size_t)bn * 256 * KK;

  const int sarr  = wid >> 1;
  const int rbase = (wid & 1) * 128;
  const unsigned short* gsrc = (sarr == 0) ? Ah : (sarr == 1) ? Al
                             : (sarr == 2) ? Wh : Wl;
  const size_t tb = (sarr < 2) ? Abase : Bbase;
  const int rowl = lane >> 2;
  const int gch  = (lane & 3) ^ ((lane >> 3) & 3);
  const unsigned short* gbase = gsrc + tb + (size_t)(rbase + rowl) * KK + gch * 8;
  unsigned short* ldst = smem + sarr * 8192 + rbase * 32;

  auto stage8 = [&](int buf, int kk) {
#pragma unroll
    for (int j = 0; j < 8; ++j) {
      __builtin_amdgcn_global_load_lds(
          (const AS1 unsigned int*)(gbase + (size_t)(j * 16) * KK + kk),
          (AS3 unsigned int*)(ldst + buf * 32768 + j * 16 * 32),
          16, 0, 0);
    }
  };

  floatx16 acc[4][2];
#pragma unroll
  for (int i = 0; i < 4; ++i)
#pragma unroll
    for (int j = 0; j < 2; ++j)
#pragma unroll
      for (int r = 0; r < 16; ++r) acc[i][j][r] = 0.f;

  stage8(0, 0);

  const int swz = (lane >> 1) & 3;
#pragma unroll
  for (int t = 0; t < 16; ++t) {
    const int cur = t & 1;
    const unsigned short* base = smem + cur * 32768;
    short8 fbh[2], fbl[2];
#pragma unroll
    for (int p = 0; p < 4; ++p) {
      const int ks = p >> 1, h = p & 1;
      const int ch = ks * 2 + (lane >> 5);
      const int sw = (ch ^ swz) * 8;
      short8 fah[2], fal[2];

      if (p == 0) {
        if (t < 15) {
          stage8(cur ^ 1, (t + 1) * GK);               // all 8, max slack
          asm volatile("s_waitcnt vmcnt(8)" ::: "memory");  // retire tile t
        } else {
          asm volatile("s_waitcnt vmcnt(0)" ::: "memory");
        }
        __builtin_amdgcn_s_barrier();                  // tile t visible
        __builtin_amdgcn_sched_barrier(0);
      }

#pragma unroll
      for (int q = 0; q < 2; ++q) {
        int row = wr * 128 + (h * 2 + q) * 32 + (lane & 31);
        fah[q] = *(const short8*)(base + row * 32 + sw);
        fal[q] = *(const short8*)(base + 8192 + row * 32 + sw);
      }
      if (h == 0) {
#pragma unroll
        for (int si = 0; si < 2; ++si) {
          int col = wc * 64 + si * 32 + (lane & 31);
          fbh[si] = *(const short8*)(base + 16384 + col * 32 + sw);
          fbl[si] = *(const short8*)(base + 24576 + col * 32 + sw);
        }
      }

      __builtin_amdgcn_s_setprio(1);
#pragma unroll
      for (int q = 0; q < 2; ++q)
#pragma unroll
        for (int si = 0; si < 2; ++si) {
          const int ri = h * 2 + q;
          acc[ri][si] = __builtin_amdgcn_mfma_f32_32x32x16_bf16(fah[q], fbh[si], acc[ri][si], 0, 0, 0);
          acc[ri][si] = __builtin_amdgcn_mfma_f32_32x32x16_bf16(fah[q], fbl[si], acc[ri][si], 0, 0, 0);
          acc[ri][si] = __builtin_amdgcn_mfma_f32_32x32x16_bf16(fal[q], fbh[si], acc[ri][si], 0, 0, 0);
        }
      __builtin_amdgcn_s_setprio(0);
      __builtin_amdgcn_sched_barrier(0);
      __builtin_amdgcn_s_barrier();                    // end-phase
    }
  }

  float bv[2];
#pragma unroll
  for (int si = 0; si < 2; ++si)
    bv[si] = bias[bn * 256 + wc * 64 + si * 32 + (lane & 31)];

  unsigned* lds32 = (unsigned*)smem;
#pragma unroll
  for (int ri = 0; ri < 4; ++ri) {
    __syncthreads();
#pragma unroll
    for (int si = 0; si < 2; ++si) {
      int lcol = wc * 64 + si * 32 + (lane & 31);
#pragma unroll
      for (int r = 0; r < 16; ++r) {
        int frow = (r & 3) + 8 * (r >> 2) + 4 * (lane >> 5);
        float v = acc[ri][si][r] + bv[si];
        if (RELU) v = fmaxf(v, 0.f);
        unsigned short h = bf16_rn(v);
        unsigned short lo = bf16_rn(v - bf16_to_f32(h));
        lds32[(wr * 32 + frow) * 256 + lcol] = (unsigned)h | ((unsigned)lo << 16);
      }
    }
    __syncthreads();
#pragma unroll
    for (int p = 0; p < 8; ++p) {
      int c = tid + p * 512;
      int lrow = c >> 6;
      int cc = (c & 63) * 4;
      uint4 d = *(const uint4*)&lds32[lrow * 256 + cc];
      ushort4 hv, lv;
      hv.x = (unsigned short)(d.x); lv.x = (unsigned short)(d.x >> 16);
      hv.y = (unsigned short)(d.y); lv.y = (unsigned short)(d.y >> 16);
      hv.z = (unsigned short)(d.z); lv.z = (unsigned short)(d.z >> 16);
      hv.w = (unsigned short)(d.w); lv.w = (unsigned short)(d.w >> 16);
      int grow = bm * 256 + (lrow >> 5) * 128 + ri * 32 + (lrow & 31);
      size_t gi = (size_t)grow * NN + bn * 256 + cc;
      *(ushort4*)&Ch[gi] = hv;
      *(ushort4*)&Cl[gi] = lv;
    }
  }
}

// ---------------------------------------------------------------------------
// GEMM layer 1: A = x (fp32) split on the fly. R10 version verbatim
// (measured 154 us at healthy clocks) -- health canary, do not touch.
// ---------------------------------------------------------------------------
__global__ __launch_bounds__(512, 1) void gemm_x(
    const float* __restrict__ X,
    const unsigned short* __restrict__ Wh, const unsigned short* __restrict__ Wl,
    const float* __restrict__ bias,
    unsigned short* __restrict__ Ch, unsigned short* __restrict__ Cl) {
  __shared__ __align__(16) unsigned short smem[65536];   // 128 KB
  const int tid = threadIdx.x;
  const int lane = tid & 63;
  const int wid = tid >> 6;
  const int wr = wid >> 2;
  const int wc = wid & 3;
  const int nwg = gridDim.x;
  const int hw  = blockIdx.x;
  const int logical = (hw & 7) * (nwg >> 3) + (hw >> 3);
  const int bm = logical >> 1, bn = logical & 1;

  const int barr = wid >> 2;
  const int brb  = (wid & 3) * 64;
  const int rowl = lane >> 2;
  const int gch  = (lane & 3) ^ ((lane >> 3) & 3);
  const unsigned short* gbB = (barr ? Wl : Wh) + (size_t)bn * 256 * KK
                            + (size_t)(brb + rowl) * KK + gch * 8;
  unsigned short* ldB = smem + (2 + barr) * 8192 + brb * 32;

  auto stageB = [&](int buf, int kk) {
#pragma unroll
    for (int j = 0; j < 4; ++j) {
      __builtin_amdgcn_global_load_lds(
          (const AS1 unsigned int*)(gbB + (size_t)(j * 16) * KK + kk),
          (AS3 unsigned int*)(ldB + buf * 32768 + j * 16 * 32),
          16, 0, 0);
    }
  };

  const int arow = lane >> 3;
  const int akc  = lane & 7;
  const float* gx = X + ((size_t)(bm * 256 + wid * 32) + arow) * KK + akc * 4;
  auto loadA = [&](int kk, float4* av) {
#pragma unroll
    for (int j = 0; j < 4; ++j)
      av[j] = *(const float4*)(gx + (size_t)(j * 8) * KK + kk);
  };
  const int apc = ((akc >> 1) ^ ((arow >> 1) & 3));
  const int aoff = (wid * 32 + arow) * 32 + apc * 8 + (akc & 1) * 4;
  auto writeA = [&](int buf, const float4* av) {
#pragma unroll
    for (int j = 0; j < 4; ++j) {
      ushort4 hv, lv;
      hv.x = bf16_rn(av[j].x); lv.x = bf16_rn(av[j].x - bf16_to_f32(hv.x));
      hv.y = bf16_rn(av[j].y); lv.y = bf16_rn(av[j].y - bf16_to_f32(hv.y));
      hv.z = bf16_rn(av[j].z); lv.z = bf16_rn(av[j].z - bf16_to_f32(hv.z));
      hv.w = bf16_rn(av[j].w); lv.w = bf16_rn(av[j].w - bf16_to_f32(hv.w));
      int o = buf * 32768 + aoff + j * 8 * 32;
      *(ushort4*)(smem + o) = hv;
      *(ushort4*)(smem + 8192 + o) = lv;
    }
  };

  floatx16 acc[4][2];
#pragma unroll
  for (int i = 0; i < 4; ++i)
#pragma unroll
    for (int j = 0; j < 2; ++j)
#pragma unroll
      for (int r = 0; r < 16; ++r) acc[i][j][r] = 0.f;

  {
    float4 av0[4];
    stageB(0, 0);
    loadA(0, av0);
    asm volatile("s_waitcnt vmcnt(0)" ::: "memory");
    writeA(0, av0);
    asm volatile("s_waitcnt lgkmcnt(0)" ::: "memory");
    __builtin_amdgcn_s_barrier();
  }

  const int swz = (lane >> 1) & 3;
#pragma unroll
  for (int t = 0; t < 16; ++t) {
    const int cur = t & 1;
    const unsigned short* base = smem + cur * 32768;
    short8 fbh[2], fbl[2];
    float4 av[4];
#pragma unroll
    for (int p = 0; p < 4; ++p) {
      const int ks = p >> 1, h = p & 1;
      const int ch = ks * 2 + (lane >> 5);
      const int sw = (ch ^ swz) * 8;
      short8 fah[2], fal[2];

      if (p == 0 && t < 15) {
        stageB(cur ^ 1, (t + 1) * GK);
        loadA((t + 1) * GK, av);
      }

#pragma unroll
      for (int q = 0; q < 2; ++q) {
        int row = wr * 128 + (h * 2 + q) * 32 + (lane & 31);
        fah[q] = *(const short8*)(base + row * 32 + sw);
        fal[q] = *(const short8*)(base + 8192 + row * 32 + sw);
      }
      if (h == 0) {
#pragma unroll
        for (int si = 0; si < 2; ++si) {
          int col = wc * 64 + si * 32 + (lane & 31);
          fbh[si] = *(const short8*)(base + 16384 + col * 32 + sw);
          fbl[si] = *(const short8*)(base + 24576 + col * 32 + sw);
        }
      }

      __builtin_amdgcn_s_setprio(1);
#pragma unroll
      for (int q = 0; q < 2; ++q)
#pragma unroll
        for (int si = 0; si < 2; ++si) {
          const int ri = h * 2 + q;
          acc[ri][si] = __builtin_amdgcn_mfma_f32_32x32x16_bf16(fah[q], fbh[si], acc[ri][si], 0, 0, 0);
          acc[ri][si] = __builtin_amdgcn_mfma_f32_32x32x16_bf16(fah[q], fbl[si], acc[ri][si], 0, 0, 0);
          acc[ri][si] = __builtin_amdgcn_mfma_f32_32x32x16_bf16(fal[q], fbh[si], acc[ri][si], 0, 0, 0);
        }
      __builtin_amdgcn_s_setprio(0);
      __builtin_amdgcn_sched_barrier(0);

      if (p == 3) {
        if (t < 15) {
          asm volatile("s_waitcnt vmcnt(0)" ::: "memory");
          writeA(cur ^ 1, av);
        }
        asm volatile("s_waitcnt lgkmcnt(0)" ::: "memory");
        __builtin_amdgcn_s_barrier();
      } else {
        __builtin_amdgcn_s_barrier();
      }
      __builtin_amdgcn_sched_barrier(0);
    }
  }

  float bv[2];
#pragma unroll
  for (int si = 0; si < 2; ++si)
    bv[si] = bias[bn * 256 + wc * 64 + si * 32 + (lane & 31)];

  unsigned* lds32 = (unsigned*)smem;
#pragma unroll
  for (int ri = 0; ri < 4; ++ri) {
    __syncthreads();
#pragma unroll
    for (int si = 0; si < 2; ++si) {
      int lcol = wc * 64 + si * 32 + (lane & 31);
#pragma unroll
      for (int r = 0; r < 16; ++r) {
        int frow = (r & 3) + 8 * (r >> 2) + 4 * (lane >> 5);
        float v = fmaxf(acc[ri][si][r] + bv[si], 0.f);
        unsigned short h = bf16_rn(v);
        unsigned short lo = bf16_rn(v - bf16_to_f32(h));
        lds32[(wr * 32 + frow) * 256 + lcol] = (unsigned)h | ((unsigned)lo << 16);
      }
    }
    __syncthreads();
#pragma unroll
    for (int p = 0; p < 8; ++p) {
      int c = tid + p * 512;
      int lrow = c >> 6;
      int cc = (c & 63) * 4;
      uint4 d = *(const uint4*)&lds32[lrow * 256 + cc];
      ushort4 hv, lv;
      hv.x = (unsigned short)(d.x); lv.x = (unsigned short)(d.x >> 16);
      hv.y = (unsigned short)(d.y); lv.y = (unsigned short)(d.y >> 16);
      hv.z = (unsigned short)(d.z); lv.z = (unsigned short)(d.z >> 16);
      hv.w = (unsigned short)(d.w); lv.w = (unsigned short)(d.w >> 16);
      int grow = bm * 256 + (lrow >> 5) * 128 + ri * 32 + (lrow & 31);
      size_t gi = (size_t)grow * NN + bn * 256 + cc;
      *(ushort4*)&Ch[gi] = hv;
      *(ushort4*)&Cl[gi] = lv;
    }
  }
}

// ---------------------------------------------------------------------------
// FUSED HEAD: all 6 prefetch loads issued at p0, vmcnt(6) -> tile-t loads
// get a full tile of latency cover (1 block/CU, thin TLP).
// ---------------------------------------------------------------------------
__global__ __launch_bounds__(512, 1) void gemm_head(
    const unsigned short* __restrict__ mh, const unsigned short* __restrict__ ml,
    const unsigned short* __restrict__ wgh, const float* __restrict__ wgb,
    const unsigned short* __restrict__ wch, const unsigned short* __restrict__ wcl,
    const float* __restrict__ bc,
    float* __restrict__ y_out, float* __restrict__ z_out) {
  __shared__ __align__(16) unsigned short smem[65792];
  const int tid = threadIdx.x;
  const int lane = tid & 63;
  const int wid = tid >> 6;
  const int wr = wid >> 2;
  const int wcs = wid & 3;
  const int bm = blockIdx.x;
  const int fr = lane & 15, fq = lane >> 4;

  const unsigned short* baseA0 = mh + (size_t)bm * 256 * KK;
  const unsigned short* baseA1 = ml + (size_t)bm * 256 * KK;
  const int rowl = lane >> 2;
  const int gch  = (lane & 3) ^ ((lane >> 3) & 3);
  const unsigned short* gb[6];
  int ldo[6];
#pragma unroll
  for (int i = 0; i < 6; ++i) {
    int s = wid * 6 + i;
    int arr = s >> 4, seg = s & 15;
    const unsigned short* b = (arr == 0) ? baseA0 : (arr == 1) ? baseA1 : wgh;
    gb[i] = b + (size_t)(seg * 16 + rowl) * KK + gch * 8;
    ldo[i] = arr * 8192 + seg * 16 * 32;
  }
  auto stage6 = [&](int buf, int kk) {
#pragma unroll
    for (int i = 0; i < 6; ++i) {
      __builtin_amdgcn_global_load_lds(
          (const AS1 unsigned int*)(gb[i] + kk),
          (AS3 unsigned int*)(smem + buf * 24576 + ldo[i]),
          16, 0, 0);
    }
  };

  const float bcv = bc[fr];
  int colv[2]; float bvmu[2];
#pragma unroll
  for (int si = 0; si < 2; ++si) {
    colv[si] = wcs * 64 + si * 32 + (lane & 31);
    bvmu[si] = wgb[colv[si]];
  }

  {
    short8 r0[2], r1[2];
#pragma unroll
    for (int q = 0; q < 2; ++q) {
      int c = tid + q * 512;
      int row = c >> 6, cc = (c & 63) * 8;
      r0[q] = *(const short8*)(wch + row * 512 + cc);
      r1[q] = *(const short8*)(wcl + row * 512 + cc);
    }
#pragma unroll
    for (int q = 0; q < 2; ++q) {
      int c = tid + q * 512;
      int row = c >> 6, cc = (c & 63) * 8;
      *(short8*)(smem + 49152 + row * 520 + cc) = r0[q];
      *(short8*)(smem + 57472 + row * 520 + cc) = r1[q];
    }
    stage6(0, 0);
    asm volatile("s_waitcnt vmcnt(0) lgkmcnt(0)" ::: "memory");
    __builtin_amdgcn_s_barrier();
  }

  floatx16 accm[4][2];
#pragma unroll
  for (int i = 0; i < 4; ++i)
#pragma unroll
    for (int j = 0; j < 2; ++j)
#pragma unroll
      for (int r = 0; r < 16; ++r) accm[i][j][r] = 0.f;
  floatx4 accl0 = {0.f, 0.f, 0.f, 0.f};
  floatx4 accl1 = {0.f, 0.f, 0.f, 0.f};

  const int swz = (lane >> 1) & 3;
  const int lsw = (fq ^ ((fr >> 1) & 3)) * 8;
#pragma unroll
  for (int t = 0; t < 16; ++t) {
    const int cur = t & 1;
    const unsigned short* base = smem + cur * 24576;
    short8 fb[2];
#pragma unroll
    for (int p = 0; p < 4; ++p) {
      const int ks = p >> 1, h = p & 1;
      const int ch = ks * 2 + (lane >> 5);
      const int sw = (ch ^ swz) * 8;
      short8 fa[2];

      if (p == 0) {
        if (t < 15) {
          stage6(cur ^ 1, (t + 1) * GK);               // all 6, max slack
          asm volatile("s_waitcnt vmcnt(6)" ::: "memory");  // retire tile t
        } else {
          asm volatile("s_waitcnt vmcnt(0)" ::: "memory");
        }
        __builtin_amdgcn_s_barrier();
        __builtin_amdgcn_sched_barrier(0);
      }

#pragma unroll
      for (int q = 0; q < 2; ++q) {
        int row = wr * 128 + (h * 2 + q) * 32 + (lane & 31);
        fa[q] = *(const short8*)(base + row * 32 + sw);
      }
      if (h == 0) {
#pragma unroll
        for (int si = 0; si < 2; ++si) {
          int col = wcs * 64 + si * 32 + (lane & 31);
          fb[si] = *(const short8*)(base + 16384 + col * 32 + sw);
        }
      }
      short8 lah, lal, lbh, lbl;
      if (p & 1) {
        const int g = p >> 1;
        int lrow = wid * 32 + g * 16 + fr;
        lah = *(const short8*)(base + lrow * 32 + lsw);
        lal = *(const short8*)(base + 8192 + lrow * 32 + lsw);
        lbh = *(const short8*)(smem + 49152 + fr * 520 + t * 32 + fq * 8);
        lbl = *(const short8*)(smem + 57472 + fr * 520 + t * 32 + fq * 8);
      }

      __builtin_amdgcn_s_setprio(1);
#pragma unroll
      for (int q = 0; q < 2; ++q)
#pragma unroll
        for (int si = 0; si < 2; ++si)
          accm[h * 2 + q][si] = __builtin_amdgcn_mfma_f32_32x32x16_bf16(fa[q], fb[si], accm[h * 2 + q][si], 0, 0, 0);
      if (p == 1) {
        accl0 = __builtin_amdgcn_mfma_f32_16x16x32_bf16(lah, lbh, accl0, 0, 0, 0);
        accl0 = __builtin_amdgcn_mfma_f32_16x16x32_bf16(lah, lbl, accl0, 0, 0, 0);
        accl0 = __builtin_amdgcn_mfma_f32_16x16x32_bf16(lal, lbh, accl0, 0, 0, 0);
      }
      if (p == 3) {
        accl1 = __builtin_amdgcn_mfma_f32_16x16x32_bf16(lah, lbh, accl1, 0, 0, 0);
        accl1 = __builtin_amdgcn_mfma_f32_16x16x32_bf16(lah, lbl, accl1, 0, 0, 0);
        accl1 = __builtin_amdgcn_mfma_f32_16x16x32_bf16(lal, lbh, accl1, 0, 0, 0);
      }
      __builtin_amdgcn_s_setprio(0);
      __builtin_amdgcn_sched_barrier(0);
      __builtin_amdgcn_s_barrier();                    // end-phase
    }
  }

  __syncthreads();
  float* slog = (float*)smem;                 // [256][17]
  float* yl = slog + 256 * 17;                // [256]
#pragma unroll
  for (int r = 0; r < 4; ++r) {
    slog[(wid * 32 + 0 * 16 + fq * 4 + r) * 17 + fr] = accl0[r] + bcv;
    slog[(wid * 32 + 1 * 16 + fq * 4 + r) * 17 + fr] = accl1[r] + bcv;
  }
  __syncthreads();
  if (tid < 256) {
    float best = slog[tid * 17];
    int bi = 0;
#pragma unroll
    for (int j = 1; j < 16; ++j) {            // strict >: first-max = np argmax
      float v = slog[tid * 17 + j];
      if (v > best) { best = v; bi = j; }
    }
    yl[tid] = (float)bi;
    y_out[(size_t)bm * 256 + tid] = (float)bi;
  }
  __syncthreads();
#pragma unroll
  for (int ri = 0; ri < 4; ++ri)
#pragma unroll
    for (int r = 0; r < 16; ++r) {
      int rowL = wr * 128 + ri * 32 + (r & 3) + 8 * (r >> 2) + 4 * (lane >> 5);
      int yv = (int)yl[rowL];
#pragma unroll
      for (int si = 0; si < 2; ++si) {
        if ((colv[si] >> 4) == yv)
          z_out[((size_t)bm * 256 + rowL) * 16 + (colv[si] & 15)] = accm[ri][si][r] + bvmu[si];
      }
    }
}

extern "C" void kernel_launch(void* const* d_in, const int* in_sizes, int n_in,
                              void* d_out, int out_size, void* d_ws, size_t ws_size,
                              hipStream_t stream) {
  const float* x  = (const float*)d_in[0];
  const float* W0 = (const float*)d_in[1];
  const float* b0 = (const float*)d_in[2];
  const float* W1 = (const float*)d_in[3];
  const float* b1 = (const float*)d_in[4];
  const float* W2 = (const float*)d_in[5];
  const float* b2 = (const float*)d_in[6];
  const float* Wc = (const float*)d_in[7];
  const float* bc = (const float*)d_in[8];
  const float* Wg = (const float*)d_in[9];
  const float* bg = (const float*)d_in[10];

  const size_t NEL = (size_t)MM * KK;
  unsigned short* Ah = (unsigned short*)d_ws;           // 64 MiB each
  unsigned short* Al = Ah + NEL;
  unsigned short* Bh = Al + NEL;
  unsigned short* Bl = Bh + NEL;
  // small weight buffers past the 4 big ones (prep_all runs first)
  unsigned short* wtail = Bl + NEL;
  unsigned short* wch = wtail;
  unsigned short* wcl = wtail + 8192;
  unsigned short* wgh = wtail + 16384;
  float* wgb = (float*)(wtail + 16384 + 131072);

  unsigned short* w0h = (unsigned short*)d_out;
  unsigned short* w0l = w0h + 262144;
  unsigned short* w1h = w0l + 262144;
  unsigned short* w1l = w1h + 262144;
  unsigned short* w2h = w1l + 262144;
  unsigned short* w2l = w2h + 262144;

  float* z_out = (float*)d_out;
  float* y_out = z_out + (size_t)MM * 16;               // at +4 MiB, clear of w-splits

  prep_all<<<904, 256, 0, stream>>>(W0, W1, W2, Wc, Wg, bg,
                                    w0h, w0l, w1h, w1l, w2h, w2l,
                                    wch, wcl, wgh, wgb);

  const int ngrid = (MM / 256) * (NN / 256);            // 512, %8==0
  gemm_x<<<ngrid, 512, 0, stream>>>(x, w0h, w0l, b0, Bh, Bl);
  gemm_mfma<true ><<<ngrid, 512, 0, stream>>>(Bh, Bl, w1h, w1l, b1, Ah, Al);
  gemm_mfma<false><<<ngrid, 512, 0, stream>>>(Ah, Al, w2h, w2l, b2, Bh, Bl);

  gemm_head<<<MM / 256, 512, 0, stream>>>(Bh, Bl, wgh, wgb, wch, wcl, bc, y_out, z_out);
}

// Round 15
// 549.595 us; speedup vs baseline: 1.2830x; 1.0254x over previous
//
#include <hip/hip_runtime.h>
#include <hip/hip_bf16.h>

typedef __attribute__((ext_vector_type(8))) short short8;
typedef __attribute__((ext_vector_type(16))) float floatx16;
typedef __attribute__((ext_vector_type(4))) float floatx4;

#define AS1 __attribute__((address_space(1)))
#define AS3 __attribute__((address_space(3)))

constexpr int MM = 65536;   // batch
constexpr int KK = 512;     // inner dim
constexpr int NN = 512;     // out dim per layer

#define GK 32

// round-to-nearest-even fp32 -> bf16 (bit-level, finite inputs)
__device__ __forceinline__ unsigned short bf16_rn(float v) {
  unsigned u = __float_as_uint(v);
  return (unsigned short)((u + 0x7FFFu + ((u >> 16) & 1u)) >> 16);
}
__device__ __forceinline__ float bf16_to_f32(unsigned short h) {
  return __uint_as_float((unsigned)h << 16);
}

// ---------------------------------------------------------------------------
// ALL weight prep in ONE launch: blocks 0..767 -> W0/W1/W2 hi/lo splits;
// 768..775 -> Wc split; 776..903 -> Wg mu-rows pack + wgb.
// ---------------------------------------------------------------------------
__global__ __launch_bounds__(256) void prep_all(
    const float* __restrict__ W0, const float* __restrict__ W1,
    const float* __restrict__ W2, const float* __restrict__ Wc,
    const float* __restrict__ Wg, const float* __restrict__ bg,
    unsigned short* __restrict__ w0h, unsigned short* __restrict__ w0l,
    unsigned short* __restrict__ w1h, unsigned short* __restrict__ w1l,
    unsigned short* __restrict__ w2h, unsigned short* __restrict__ w2l,
    unsigned short* __restrict__ wch, unsigned short* __restrict__ wcl,
    unsigned short* __restrict__ wgh, float* __restrict__ wgb) {
  const int b = blockIdx.x;
  if (b < 776) {
    const float* src; unsigned short* h; unsigned short* l; int i;
    if (b < 256)      { src = W0; h = w0h; l = w0l; i = b * 256 + threadIdx.x; }
    else if (b < 512) { src = W1; h = w1h; l = w1l; i = (b - 256) * 256 + threadIdx.x; }
    else if (b < 768) { src = W2; h = w2h; l = w2l; i = (b - 512) * 256 + threadIdx.x; }
    else              { src = Wc; h = wch; l = wcl; i = (b - 768) * 256 + threadIdx.x; }
    float4 v = ((const float4*)src)[i];
    ushort4 hv, lv;
    hv.x = bf16_rn(v.x); lv.x = bf16_rn(v.x - bf16_to_f32(hv.x));
    hv.y = bf16_rn(v.y); lv.y = bf16_rn(v.y - bf16_to_f32(hv.y));
    hv.z = bf16_rn(v.z); lv.z = bf16_rn(v.z - bf16_to_f32(hv.z));
    hv.w = bf16_rn(v.w); lv.w = bf16_rn(v.w - bf16_to_f32(hv.w));
    ((ushort4*)h)[i] = hv;
    ((ushort4*)l)[i] = lv;
  } else {
    int gid = (b - 776) * 256 + threadIdx.x;   // 0..32767
    int r = gid >> 7;
    int c4 = (gid & 127) * 4;
    int k = r >> 4, e = r & 15;
    float4 v = *(const float4*)(Wg + ((size_t)k * 32 + e) * 512 + c4);
    ushort4 h;
    h.x = bf16_rn(v.x); h.y = bf16_rn(v.y); h.z = bf16_rn(v.z); h.w = bf16_rn(v.w);
    *(ushort4*)(wgh + (size_t)r * 512 + c4) = h;
    if (c4 == 0) wgb[r] = bg[k * 32 + e];
  }
}

// ---------------------------------------------------------------------------
// GEMM layers 2,3: 4-phase interleave, R14 staggered staging (2 gloads per
// phase, vmcnt(2) at p0). R16: barriers thinned to TWO per K-tile --
// p0-entry (tile publish, after counted vmcnt) and p3-end (buffer handoff:
// next tile's p0 stage writes into `cur`). p0/p1/p2-end were pacing-only.
// ---------------------------------------------------------------------------
template<bool RELU>
__global__ __launch_bounds__(512, 1) void gemm_mfma(
    const unsigned short* __restrict__ Ah, const unsigned short* __restrict__ Al,
    const unsigned short* __restrict__ Wh, const unsigned short* __restrict__ Wl,
    const float* __restrict__ bias,
    unsigned short* __restrict__ Ch, unsigned short* __restrict__ Cl) {
  __shared__ __align__(16) unsigned short smem[65536];   // 128 KB
  const int tid = threadIdx.x;
  const int lane = tid & 63;
  const int wid = tid >> 6;
  const int wr = wid >> 2;
  const int wc = wid & 3;
  const int nwg = gridDim.x;
  const int hw  = blockIdx.x;
  const int logical = (hw & 7) * (nwg >> 3) + (hw >> 3);
  const int bm = logical >> 1, bn = logical & 1;
  const size_t Abase = (size_t)bm * 256 * KK;
  const size_t Bbase = (size_t)bn * 256 * KK;

  const int sarr  = wid >> 1;
  const int rbase = (wid & 1) * 128;
  const unsigned short* gsrc = (sarr == 0) ? Ah : (sarr == 1) ? Al
                             : (sarr == 2) ? Wh : Wl;
  const size_t tb = (sarr < 2) ? Abase : Bbase;
  const int rowl = lane >> 2;
  const int gch  = (lane & 3) ^ ((lane >> 3) & 3);
  const unsigned short* gbase = gsrc + tb + (size_t)(rbase + rowl) * KK + gch * 8;
  unsigned short* ldst = smem + sarr * 8192 + rbase * 32;

  auto stage2 = [&](int buf, int kk, int p) {
#pragma unroll
    for (int j = p * 2; j < p * 2 + 2; ++j) {
      __builtin_amdgcn_global_load_lds(
          (const AS1 unsigned int*)(gbase + (size_t)(j * 16) * KK + kk),
          (AS3 unsigned int*)(ldst + buf * 32768 + j * 16 * 32),
          16, 0, 0);
    }
  };

  floatx16 acc[4][2];
#pragma unroll
  for (int i = 0; i < 4; ++i)
#pragma unroll
    for (int j = 0; j < 2; ++j)
#pragma unroll
      for (int r = 0; r < 16; ++r) acc[i][j][r] = 0.f;

#pragma unroll
  for (int p = 0; p < 4; ++p) stage2(0, 0, p);

  const int swz = (lane >> 1) & 3;
#pragma unroll
  for (int t = 0; t < 16; ++t) {
    const int cur = t & 1;
    const unsigned short* base = smem + cur * 32768;
    short8 fbh[2], fbl[2];
#pragma unroll
    for (int p = 0; p < 4; ++p) {
      const int ks = p >> 1, h = p & 1;
      const int ch = ks * 2 + (lane >> 5);
      const int sw = (ch ^ swz) * 8;
      short8 fah[2], fal[2];

      if (p == 0) {
        if (t < 15) {
          stage2(cur ^ 1, (t + 1) * GK, 0);
          asm volatile("s_waitcnt vmcnt(2)" ::: "memory");
        } else {
          asm volatile("s_waitcnt vmcnt(0)" ::: "memory");
        }
        __builtin_amdgcn_s_barrier();                  // tile t visible
        __builtin_amdgcn_sched_barrier(0);
      }

#pragma unroll
      for (int q = 0; q < 2; ++q) {
        int row = wr * 128 + (h * 2 + q) * 32 + (lane & 31);
        fah[q] = *(const short8*)(base + row * 32 + sw);
        fal[q] = *(const short8*)(base + 8192 + row * 32 + sw);
      }
      if (h == 0) {
#pragma unroll
        for (int si = 0; si < 2; ++si) {
          int col = wc * 64 + si * 32 + (lane & 31);
          fbh[si] = *(const short8*)(base + 16384 + col * 32 + sw);
          fbl[si] = *(const short8*)(base + 24576 + col * 32 + sw);
        }
      }

      if (p > 0) {
        if (t < 15) stage2(cur ^ 1, (t + 1) * GK, p);
        __builtin_amdgcn_sched_barrier(0);
      }

      __builtin_amdgcn_s_setprio(1);
#pragma unroll
      for (int q = 0; q < 2; ++q)
#pragma unroll
        for (int si = 0; si < 2; ++si) {
          const int ri = h * 2 + q;
          acc[ri][si] = __builtin_amdgcn_mfma_f32_32x32x16_bf16(fah[q], fbh[si], acc[ri][si], 0, 0, 0);
          acc[ri][si] = __builtin_amdgcn_mfma_f32_32x32x16_bf16(fah[q], fbl[si], acc[ri][si], 0, 0, 0);
          acc[ri][si] = __builtin_amdgcn_mfma_f32_32x32x16_bf16(fal[q], fbh[si], acc[ri][si], 0, 0, 0);
        }
      __builtin_amdgcn_s_setprio(0);
      __builtin_amdgcn_sched_barrier(0);
      if (p == 3) __builtin_amdgcn_s_barrier();        // handoff barrier only
    }
  }

  float bv[2];
#pragma unroll
  for (int si = 0; si < 2; ++si)
    bv[si] = bias[bn * 256 + wc * 64 + si * 32 + (lane & 31)];

  unsigned* lds32 = (unsigned*)smem;
#pragma unroll
  for (int ri = 0; ri < 4; ++ri) {
    __syncthreads();
#pragma unroll
    for (int si = 0; si < 2; ++si) {
      int lcol = wc * 64 + si * 32 + (lane & 31);
#pragma unroll
      for (int r = 0; r < 16; ++r) {
        int frow = (r & 3) + 8 * (r >> 2) + 4 * (lane >> 5);
        float v = acc[ri][si][r] + bv[si];
        if (RELU) v = fmaxf(v, 0.f);
        unsigned short h = bf16_rn(v);
        unsigned short lo = bf16_rn(v - bf16_to_f32(h));
        lds32[(wr * 32 + frow) * 256 + lcol] = (unsigned)h | ((unsigned)lo << 16);
      }
    }
    __syncthreads();
#pragma unroll
    for (int p = 0; p < 8; ++p) {
      int c = tid + p * 512;
      int lrow = c >> 6;
      int cc = (c & 63) * 4;
      uint4 d = *(const uint4*)&lds32[lrow * 256 + cc];
      ushort4 hv, lv;
      hv.x = (unsigned short)(d.x); lv.x = (unsigned short)(d.x >> 16);
      hv.y = (unsigned short)(d.y); lv.y = (unsigned short)(d.y >> 16);
      hv.z = (unsigned short)(d.z); lv.z = (unsigned short)(d.z >> 16);
      hv.w = (unsigned short)(d.w); lv.w = (unsigned short)(d.w >> 16);
      int grow = bm * 256 + (lrow >> 5) * 128 + ri * 32 + (lrow & 31);
      size_t gi = (size_t)grow * NN + bn * 256 + cc;
      *(ushort4*)&Ch[gi] = hv;
      *(ushort4*)&Cl[gi] = lv;
    }
  }
}

// ---------------------------------------------------------------------------
// GEMM layer 1: A = x (fp32) split on the fly. R10 version verbatim
// (measured 154 us at healthy clocks) -- health canary, do not touch.
// ---------------------------------------------------------------------------
__global__ __launch_bounds__(512, 1) void gemm_x(
    const float* __restrict__ X,
    const unsigned short* __restrict__ Wh, const unsigned short* __restrict__ Wl,
    const float* __restrict__ bias,
    unsigned short* __restrict__ Ch, unsigned short* __restrict__ Cl) {
  __shared__ __align__(16) unsigned short smem[65536];   // 128 KB
  const int tid = threadIdx.x;
  const int lane = tid & 63;
  const int wid = tid >> 6;
  const int wr = wid >> 2;
  const int wc = wid & 3;
  const int nwg = gridDim.x;
  const int hw  = blockIdx.x;
  const int logical = (hw & 7) * (nwg >> 3) + (hw >> 3);
  const int bm = logical >> 1, bn = logical & 1;

  const int barr = wid >> 2;
  const int brb  = (wid & 3) * 64;
  const int rowl = lane >> 2;
  const int gch  = (lane & 3) ^ ((lane >> 3) & 3);
  const unsigned short* gbB = (barr ? Wl : Wh) + (size_t)bn * 256 * KK
                            + (size_t)(brb + rowl) * KK + gch * 8;
  unsigned short* ldB = smem + (2 + barr) * 8192 + brb * 32;

  auto stageB = [&](int buf, int kk) {
#pragma unroll
    for (int j = 0; j < 4; ++j) {
      __builtin_amdgcn_global_load_lds(
          (const AS1 unsigned int*)(gbB + (size_t)(j * 16) * KK + kk),
          (AS3 unsigned int*)(ldB + buf * 32768 + j * 16 * 32),
          16, 0, 0);
    }
  };

  const int arow = lane >> 3;
  const int akc  = lane & 7;
  const float* gx = X + ((size_t)(bm * 256 + wid * 32) + arow) * KK + akc * 4;
  auto loadA = [&](int kk, float4* av) {
#pragma unroll
    for (int j = 0; j < 4; ++j)
      av[j] = *(const float4*)(gx + (size_t)(j * 8) * KK + kk);
  };
  const int apc = ((akc >> 1) ^ ((arow >> 1) & 3));
  const int aoff = (wid * 32 + arow) * 32 + apc * 8 + (akc & 1) * 4;
  auto writeA = [&](int buf, const float4* av) {
#pragma unroll
    for (int j = 0; j < 4; ++j) {
      ushort4 hv, lv;
      hv.x = bf16_rn(av[j].x); lv.x = bf16_rn(av[j].x - bf16_to_f32(hv.x));
      hv.y = bf16_rn(av[j].y); lv.y = bf16_rn(av[j].y - bf16_to_f32(hv.y));
      hv.z = bf16_rn(av[j].z); lv.z = bf16_rn(av[j].z - bf16_to_f32(hv.z));
      hv.w = bf16_rn(av[j].w); lv.w = bf16_rn(av[j].w - bf16_to_f32(hv.w));
      int o = buf * 32768 + aoff + j * 8 * 32;
      *(ushort4*)(smem + o) = hv;
      *(ushort4*)(smem + 8192 + o) = lv;
    }
  };

  floatx16 acc[4][2];
#pragma unroll
  for (int i = 0; i < 4; ++i)
#pragma unroll
    for (int j = 0; j < 2; ++j)
#pragma unroll
      for (int r = 0; r < 16; ++r) acc[i][j][r] = 0.f;

  {
    float4 av0[4];
    stageB(0, 0);
    loadA(0, av0);
    asm volatile("s_waitcnt vmcnt(0)" ::: "memory");
    writeA(0, av0);
    asm volatile("s_waitcnt lgkmcnt(0)" ::: "memory");
    __builtin_amdgcn_s_barrier();
  }

  const int swz = (lane >> 1) & 3;
#pragma unroll
  for (int t = 0; t < 16; ++t) {
    const int cur = t & 1;
    const unsigned short* base = smem + cur * 32768;
    short8 fbh[2], fbl[2];
    float4 av[4];
#pragma unroll
    for (int p = 0; p < 4; ++p) {
      const int ks = p >> 1, h = p & 1;
      const int ch = ks * 2 + (lane >> 5);
      const int sw = (ch ^ swz) * 8;
      short8 fah[2], fal[2];

      if (p == 0 && t < 15) {
        stageB(cur ^ 1, (t + 1) * GK);
        loadA((t + 1) * GK, av);
      }

#pragma unroll
      for (int q = 0; q < 2; ++q) {
        int row = wr * 128 + (h * 2 + q) * 32 + (lane & 31);
        fah[q] = *(const short8*)(base + row * 32 + sw);
        fal[q] = *(const short8*)(base + 8192 + row * 32 + sw);
      }
      if (h == 0) {
#pragma unroll
        for (int si = 0; si < 2; ++si) {
          int col = wc * 64 + si * 32 + (lane & 31);
          fbh[si] = *(const short8*)(base + 16384 + col * 32 + sw);
          fbl[si] = *(const short8*)(base + 24576 + col * 32 + sw);
        }
      }

      __builtin_amdgcn_s_setprio(1);
#pragma unroll
      for (int q = 0; q < 2; ++q)
#pragma unroll
        for (int si = 0; si < 2; ++si) {
          const int ri = h * 2 + q;
          acc[ri][si] = __builtin_amdgcn_mfma_f32_32x32x16_bf16(fah[q], fbh[si], acc[ri][si], 0, 0, 0);
          acc[ri][si] = __builtin_amdgcn_mfma_f32_32x32x16_bf16(fah[q], fbl[si], acc[ri][si], 0, 0, 0);
          acc[ri][si] = __builtin_amdgcn_mfma_f32_32x32x16_bf16(fal[q], fbh[si], acc[ri][si], 0, 0, 0);
        }
      __builtin_amdgcn_s_setprio(0);
      __builtin_amdgcn_sched_barrier(0);

      if (p == 3) {
        if (t < 15) {
          asm volatile("s_waitcnt vmcnt(0)" ::: "memory");
          writeA(cur ^ 1, av);
        }
        asm volatile("s_waitcnt lgkmcnt(0)" ::: "memory");
        __builtin_amdgcn_s_barrier();
      } else {
        __builtin_amdgcn_s_barrier();
      }
      __builtin_amdgcn_sched_barrier(0);
    }
  }

  float bv[2];
#pragma unroll
  for (int si = 0; si < 2; ++si)
    bv[si] = bias[bn * 256 + wc * 64 + si * 32 + (lane & 31)];

  unsigned* lds32 = (unsigned*)smem;
#pragma unroll
  for (int ri = 0; ri < 4; ++ri) {
    __syncthreads();
#pragma unroll
    for (int si = 0; si < 2; ++si) {
      int lcol = wc * 64 + si * 32 + (lane & 31);
#pragma unroll
      for (int r = 0; r < 16; ++r) {
        int frow = (r & 3) + 8 * (r >> 2) + 4 * (lane >> 5);
        float v = fmaxf(acc[ri][si][r] + bv[si], 0.f);
        unsigned short h = bf16_rn(v);
        unsigned short lo = bf16_rn(v - bf16_to_f32(h));
        lds32[(wr * 32 + frow) * 256 + lcol] = (unsigned)h | ((unsigned)lo << 16);
      }
    }
    __syncthreads();
#pragma unroll
    for (int p = 0; p < 8; ++p) {
      int c = tid + p * 512;
      int lrow = c >> 6;
      int cc = (c & 63) * 4;
      uint4 d = *(const uint4*)&lds32[lrow * 256 + cc];
      ushort4 hv, lv;
      hv.x = (unsigned short)(d.x); lv.x = (unsigned short)(d.x >> 16);
      hv.y = (unsigned short)(d.y); lv.y = (unsigned short)(d.y >> 16);
      hv.z = (unsigned short)(d.z); lv.z = (unsigned short)(d.z >> 16);
      hv.w = (unsigned short)(d.w); lv.w = (unsigned short)(d.w >> 16);
      int grow = bm * 256 + (lrow >> 5) * 128 + ri * 32 + (lrow & 31);
      size_t gi = (size_t)grow * NN + bn * 256 + cc;
      *(ushort4*)&Ch[gi] = hv;
      *(ushort4*)&Cl[gi] = lv;
    }
  }
}

// ---------------------------------------------------------------------------
// FUSED HEAD: R14 staggered staging (2 gloads at p0/p1/p2, vmcnt(2));
// R16 barrier thinning: p0-entry + p3-end only.
// ---------------------------------------------------------------------------
__global__ __launch_bounds__(512, 1) void gemm_head(
    const unsigned short* __restrict__ mh, const unsigned short* __restrict__ ml,
    const unsigned short* __restrict__ wgh, const float* __restrict__ wgb,
    const unsigned short* __restrict__ wch, const unsigned short* __restrict__ wcl,
    const float* __restrict__ bc,
    float* __restrict__ y_out, float* __restrict__ z_out) {
  __shared__ __align__(16) unsigned short smem[65792];
  const int tid = threadIdx.x;
  const int lane = tid & 63;
  const int wid = tid >> 6;
  const int wr = wid >> 2;
  const int wcs = wid & 3;
  const int bm = blockIdx.x;
  const int fr = lane & 15, fq = lane >> 4;

  const unsigned short* baseA0 = mh + (size_t)bm * 256 * KK;
  const unsigned short* baseA1 = ml + (size_t)bm * 256 * KK;
  const int rowl = lane >> 2;
  const int gch  = (lane & 3) ^ ((lane >> 3) & 3);
  const unsigned short* gb[6];
  int ldo[6];
#pragma unroll
  for (int i = 0; i < 6; ++i) {
    int s = wid * 6 + i;
    int arr = s >> 4, seg = s & 15;
    const unsigned short* b = (arr == 0) ? baseA0 : (arr == 1) ? baseA1 : wgh;
    gb[i] = b + (size_t)(seg * 16 + rowl) * KK + gch * 8;
    ldo[i] = arr * 8192 + seg * 16 * 32;
  }
  auto stageH = [&](int buf, int kk, int i) {
    __builtin_amdgcn_global_load_lds(
        (const AS1 unsigned int*)(gb[i] + kk),
        (AS3 unsigned int*)(smem + buf * 24576 + ldo[i]),
        16, 0, 0);
  };

  const float bcv = bc[fr];
  int colv[2]; float bvmu[2];
#pragma unroll
  for (int si = 0; si < 2; ++si) {
    colv[si] = wcs * 64 + si * 32 + (lane & 31);
    bvmu[si] = wgb[colv[si]];
  }

  {
    short8 r0[2], r1[2];
#pragma unroll
    for (int q = 0; q < 2; ++q) {
      int c = tid + q * 512;
      int row = c >> 6, cc = (c & 63) * 8;
      r0[q] = *(const short8*)(wch + row * 512 + cc);
      r1[q] = *(const short8*)(wcl + row * 512 + cc);
    }
#pragma unroll
    for (int q = 0; q < 2; ++q) {
      int c = tid + q * 512;
      int row = c >> 6, cc = (c & 63) * 8;
      *(short8*)(smem + 49152 + row * 520 + cc) = r0[q];
      *(short8*)(smem + 57472 + row * 520 + cc) = r1[q];
    }
#pragma unroll
    for (int i = 0; i < 6; ++i) stageH(0, 0, i);
    asm volatile("s_waitcnt vmcnt(0) lgkmcnt(0)" ::: "memory");
    __builtin_amdgcn_s_barrier();
  }

  floatx16 accm[4][2];
#pragma unroll
  for (int i = 0; i < 4; ++i)
#pragma unroll
    for (int j = 0; j < 2; ++j)
#pragma unroll
      for (int r = 0; r < 16; ++r) accm[i][j][r] = 0.f;
  floatx4 accl0 = {0.f, 0.f, 0.f, 0.f};
  floatx4 accl1 = {0.f, 0.f, 0.f, 0.f};

  const int swz = (lane >> 1) & 3;
  const int lsw = (fq ^ ((fr >> 1) & 3)) * 8;
#pragma unroll
  for (int t = 0; t < 16; ++t) {
    const int cur = t & 1;
    const unsigned short* base = smem + cur * 24576;
    short8 fb[2];
#pragma unroll
    for (int p = 0; p < 4; ++p) {
      const int ks = p >> 1, h = p & 1;
      const int ch = ks * 2 + (lane >> 5);
      const int sw = (ch ^ swz) * 8;
      short8 fa[2];

      if (p == 0) {
        if (t < 15) {
          stageH(cur ^ 1, (t + 1) * GK, 0);
          stageH(cur ^ 1, (t + 1) * GK, 1);
          asm volatile("s_waitcnt vmcnt(2)" ::: "memory");
        } else {
          asm volatile("s_waitcnt vmcnt(0)" ::: "memory");
        }
        __builtin_amdgcn_s_barrier();
        __builtin_amdgcn_sched_barrier(0);
      }

#pragma unroll
      for (int q = 0; q < 2; ++q) {
        int row = wr * 128 + (h * 2 + q) * 32 + (lane & 31);
        fa[q] = *(const short8*)(base + row * 32 + sw);
      }
      if (h == 0) {
#pragma unroll
        for (int si = 0; si < 2; ++si) {
          int col = wcs * 64 + si * 32 + (lane & 31);
          fb[si] = *(const short8*)(base + 16384 + col * 32 + sw);
        }
      }
      short8 lah, lal, lbh, lbl;
      if (p & 1) {
        const int g = p >> 1;
        int lrow = wid * 32 + g * 16 + fr;
        lah = *(const short8*)(base + lrow * 32 + lsw);
        lal = *(const short8*)(base + 8192 + lrow * 32 + lsw);
        lbh = *(const short8*)(smem + 49152 + fr * 520 + t * 32 + fq * 8);
        lbl = *(const short8*)(smem + 57472 + fr * 520 + t * 32 + fq * 8);
      }

      if (p > 0) {
        if (t < 15 && p < 3) {
          stageH(cur ^ 1, (t + 1) * GK, p * 2);
          stageH(cur ^ 1, (t + 1) * GK, p * 2 + 1);
        }
        __builtin_amdgcn_sched_barrier(0);
      }

      __builtin_amdgcn_s_setprio(1);
#pragma unroll
      for (int q = 0; q < 2; ++q)
#pragma unroll
        for (int si = 0; si < 2; ++si)
          accm[h * 2 + q][si] = __builtin_amdgcn_mfma_f32_32x32x16_bf16(fa[q], fb[si], accm[h * 2 + q][si], 0, 0, 0);
      if (p == 1) {
        accl0 = __builtin_amdgcn_mfma_f32_16x16x32_bf16(lah, lbh, accl0, 0, 0, 0);
        accl0 = __builtin_amdgcn_mfma_f32_16x16x32_bf16(lah, lbl, accl0, 0, 0, 0);
        accl0 = __builtin_amdgcn_mfma_f32_16x16x32_bf16(lal, lbh, accl0, 0, 0, 0);
      }
      if (p == 3) {
        accl1 = __builtin_amdgcn_mfma_f32_16x16x32_bf16(lah, lbh, accl1, 0, 0, 0);
        accl1 = __builtin_amdgcn_mfma_f32_16x16x32_bf16(lah, lbl, accl1, 0, 0, 0);
        accl1 = __builtin_amdgcn_mfma_f32_16x16x32_bf16(lal, lbh, accl1, 0, 0, 0);
      }
      __builtin_amdgcn_s_setprio(0);
      __builtin_amdgcn_sched_barrier(0);
      if (p == 3) __builtin_amdgcn_s_barrier();        // handoff barrier only
    }
  }

  __syncthreads();
  float* slog = (float*)smem;                 // [256][17]
  float* yl = slog + 256 * 17;                // [256]
#pragma unroll
  for (int r = 0; r < 4; ++r) {
    slog[(wid * 32 + 0 * 16 + fq * 4 + r) * 17 + fr] = accl0[r] + bcv;
    slog[(wid * 32 + 1 * 16 + fq * 4 + r) * 17 + fr] = accl1[r] + bcv;
  }
  __syncthreads();
  if (tid < 256) {
    float best = slog[tid * 17];
    int bi = 0;
#pragma unroll
    for (int j = 1; j < 16; ++j) {            // strict >: first-max = np argmax
      float v = slog[tid * 17 + j];
      if (v > best) { best = v; bi = j; }
    }
    yl[tid] = (float)bi;
    y_out[(size_t)bm * 256 + tid] = (float)bi;
  }
  __syncthreads();
#pragma unroll
  for (int ri = 0; ri < 4; ++ri)
#pragma unroll
    for (int r = 0; r < 16; ++r) {
      int rowL = wr * 128 + ri * 32 + (r & 3) + 8 * (r >> 2) + 4 * (lane >> 5);
      int yv = (int)yl[rowL];
#pragma unroll
      for (int si = 0; si < 2; ++si) {
        if ((colv[si] >> 4) == yv)
          z_out[((size_t)bm * 256 + rowL) * 16 + (colv[si] & 15)] = accm[ri][si][r] + bvmu[si];
      }
    }
}

extern "C" void kernel_launch(void* const* d_in, const int* in_sizes, int n_in,
                              void* d_out, int out_size, void* d_ws, size_t ws_size,
                              hipStream_t stream) {
  const float* x  = (const float*)d_in[0];
  const float* W0 = (const float*)d_in[1];
  const float* b0 = (const float*)d_in[2];
  const float* W1 = (const float*)d_in[3];
  const float* b1 = (const float*)d_in[4];
  const float* W2 = (const float*)d_in[5];
  const float* b2 = (const float*)d_in[6];
  const float* Wc = (const float*)d_in[7];
  const float* bc = (const float*)d_in[8];
  const float* Wg = (const float*)d_in[9];
  const float* bg = (const float*)d_in[10];

  const size_t NEL = (size_t)MM * KK;
  unsigned short* Ah = (unsigned short*)d_ws;           // 64 MiB each
  unsigned short* Al = Ah + NEL;
  unsigned short* Bh = Al + NEL;
  unsigned short* Bl = Bh + NEL;
  // small weight buffers past the 4 big ones (prep_all runs first)
  unsigned short* wtail = Bl + NEL;
  unsigned short* wch = wtail;
  unsigned short* wcl = wtail + 8192;
  unsigned short* wgh = wtail + 16384;
  float* wgb = (float*)(wtail + 16384 + 131072);

  unsigned short* w0h = (unsigned short*)d_out;
  unsigned short* w0l = w0h + 262144;
  unsigned short* w1h = w0l + 262144;
  unsigned short* w1l = w1h + 262144;
  unsigned short* w2h = w1l + 262144;
  unsigned short* w2l = w2h + 262144;

  float* z_out = (float*)d_out;
  float* y_out = z_out + (size_t)MM * 16;               // at +4 MiB, clear of w-splits

  prep_all<<<904, 256, 0, stream>>>(W0, W1, W2, Wc, Wg, bg,
                                    w0h, w0l, w1h, w1l, w2h, w2l,
                                    wch, wcl, wgh, wgb);

  const int ngrid = (MM / 256) * (NN / 256);            // 512, %8==0
  gemm_x<<<ngrid, 512, 0, stream>>>(x, w0h, w0l, b0, Bh, Bl);
  gemm_mfma<true ><<<ngrid, 512, 0, stream>>>(Bh, Bl, w1h, w1l, b1, Ah, Al);
  gemm_mfma<false><<<ngrid, 512, 0, stream>>>(Ah, Al, w2h, w2l, b2, Bh, Bl);

  gemm_head<<<MM / 256, 512, 0, stream>>>(Bh, Bl, wgh, wgb, wch, wcl, bc, y_out, z_out);
}